// Round 3
// baseline (1749.354 us; speedup 1.0000x reference)
//
#include <hip/hip_runtime.h>
#include <hip/hip_bf16.h>

// RelPartialLearnableMultiHeadAttn (Transformer-XL) on MI355X.
// Shapes: QLEN=KLEN=RLEN=2048, BSZ=2, NH=16, DH=64, DM=1024. SCALE=0.125.
// R6: R5's in-block k-split merge pushed VGPR 60->76, crossing the 64-VGPR
// occupancy cliff (32->16 waves/CU cap) -- occupancy FELL to 31%. Fix:
// split the softmax merge ACROSS KERNELS instead of across waves:
//   attn_passA: l = sum(exp(s)) per k-half -> lpart[z][bn][q]   (VGPR<=64)
//   attn_passB: p = exp(s)*(1/(l0+l1)) -> coverage + PV partial -> AVp[z]
//   gemm64f<0>: stages A = AVp0 + AVp1 (merge folded into output GEMM)
// Per-wave inner loop identical to the proven R4/R5 scores() (sliding-band
// BD MFMA + same-quad shuffle, max-free softmax).

#define QL 2048
#define KL 2048
#define RL 2048
#define BS 2
#define NHD 16
#define DH 64
#define DM 1024

typedef __hip_bfloat16 bf16;
typedef short v8s __attribute__((ext_vector_type(8)));
typedef float v4f __attribute__((ext_vector_type(4)));

__device__ __forceinline__ bf16 f2b(float x) { return __float2bfloat16(x); }
__device__ __forceinline__ short f2s(float x) {
    return __builtin_bit_cast(short, __float2bfloat16(x));
}

// ---------------------------------------------------------------------------
// 64x64-tile GEMM, C = A(MxK) @ B(KxN), A/B row-major FLOAT32; bf16 MFMA.
// A2 (optional, EPI 0): A is read as A+A2 elementwise (AV partial merge).
// EPI 0: f32 C write. EPI 1: qkv scatter (+r_r_bias into Qb; Wv transposed),
// bf16 out. EPI 2: Rk scatter [n][r][d], bf16 out.
// ---------------------------------------------------------------------------
template <int EPI>
__global__ __launch_bounds__(256) void gemm64f(
    const float* __restrict__ A, const float* __restrict__ A2,
    const float* __restrict__ B,
    int M, int N, int K,
    float* __restrict__ C,
    bf16* __restrict__ Qb, bf16* __restrict__ Wk, bf16* __restrict__ Wvt,
    bf16* __restrict__ Rk, const float* __restrict__ rrb)
{
    __shared__ short As[64][40];   // +8 pad; row stride 80 B (16B-aligned)
    __shared__ short Bs[64][40];   // transposed: Bs[n][k]
    const int n0 = blockIdx.x * 64, m0 = blockIdx.y * 64;
    const int t = threadIdx.x, w = t >> 6, lane = t & 63;
    const int quad = lane >> 4, lr = lane & 15;

    v4f acc[4] = {};
    for (int k0 = 0; k0 < K; k0 += 32) {
        {   // A tile 64x32 f32 -> bf16 LDS: row = t>>2, 8 floats per thread
            const int row = t >> 2, cg = (t & 3) << 3;
            const size_t aoff = (size_t)(m0 + row) * K + k0 + cg;
            float4 a0 = *(const float4*)(A + aoff);
            float4 a1 = *(const float4*)(A + aoff + 4);
            if (EPI == 0 && A2 != nullptr) {
                float4 c0 = *(const float4*)(A2 + aoff);
                float4 c1 = *(const float4*)(A2 + aoff + 4);
                a0.x += c0.x; a0.y += c0.y; a0.z += c0.z; a0.w += c0.w;
                a1.x += c1.x; a1.y += c1.y; a1.z += c1.z; a1.w += c1.w;
            }
            v8s pk;
            pk[0] = f2s(a0.x); pk[1] = f2s(a0.y); pk[2] = f2s(a0.z); pk[3] = f2s(a0.w);
            pk[4] = f2s(a1.x); pk[5] = f2s(a1.y); pk[6] = f2s(a1.z); pk[7] = f2s(a1.w);
            *(v8s*)&As[row][cg] = pk;
            // B tile 32x64 f32 -> transposed bf16 LDS: kk = t>>3, 8 floats
            const int kk = t >> 3, ng = (t & 7) << 3;
            const float* bp = B + (size_t)(k0 + kk) * N + n0 + ng;
            float4 b0 = *(const float4*)bp;
            float4 b1 = *(const float4*)(bp + 4);
            Bs[ng + 0][kk] = f2s(b0.x); Bs[ng + 1][kk] = f2s(b0.y);
            Bs[ng + 2][kk] = f2s(b0.z); Bs[ng + 3][kk] = f2s(b0.w);
            Bs[ng + 4][kk] = f2s(b1.x); Bs[ng + 5][kk] = f2s(b1.y);
            Bs[ng + 6][kk] = f2s(b1.z); Bs[ng + 7][kk] = f2s(b1.w);
        }
        __syncthreads();
        v8s af = *(const v8s*)&As[16 * w + lr][quad * 8];
#pragma unroll
        for (int ct = 0; ct < 4; ++ct) {
            v8s bfm = *(const v8s*)&Bs[ct * 16 + lr][quad * 8];
            acc[ct] = __builtin_amdgcn_mfma_f32_16x16x32_bf16(af, bfm, acc[ct], 0, 0, 0);
        }
        __syncthreads();
    }

#pragma unroll
    for (int ct = 0; ct < 4; ++ct) {
#pragma unroll
        for (int r = 0; r < 4; ++r) {
            const int gm = m0 + 16 * w + quad * 4 + r;   // C row
            const int gn = n0 + ct * 16 + lr;            // C col
            float v = acc[ct][r];
            if constexpr (EPI == 0) {
                C[(size_t)gm * N + gn] = v;
            } else if constexpr (EPI == 1) {
                const int q = gm >> 1, b = gm & 1;       // w rows are (q, b)
                const int sec = gn >> 10, idx = gn & 1023;
                const int n = idx >> 6, d = idx & 63;
                const size_t bn = (size_t)(b * NHD + n);
                if (sec == 0) {
                    v += rrb[n * 64 + d];                // Qb = wq + r_r_bias
                    Qb[(bn * QL + q) * DH + d] = f2b(v);
                } else if (sec == 1) {
                    Wk[(bn * KL + q) * DH + d] = f2b(v);
                } else {
                    Wvt[(bn * DH + d) * KL + q] = f2b(v); // transposed [d][k]
                }
            } else {  // EPI == 2 : Rk[n][r][d]
                const int n = gn >> 6, d = gn & 63;
                Rk[((size_t)n * RL + gm) * DH + d] = f2b(v);
            }
        }
    }
}

// ---------------------------------------------------------------------------
// Pass A: l[bn][q] partial over this block's k-half. Grid (QL/64, 32, 2).
// Per-wave loop identical to R4's scores(); no PV/cov state -> low VGPR;
// __launch_bounds__(256,8) pins <=64 VGPR -> 32 waves/CU.
// ---------------------------------------------------------------------------
__global__ __launch_bounds__(256, 8) void attn_passA(
    const bf16* __restrict__ Qb, const bf16* __restrict__ Wk,
    const bf16* __restrict__ Rk, const int* __restrict__ mask,
    float* __restrict__ lpart)
{
    __shared__ short mlds[KL / 2];
    const int bn = blockIdx.y, b = bn >> 4, n = bn & 15;
    const int z = blockIdx.z;
    const int t = threadIdx.x, w = t >> 6, lane = t & 63;
    const int quad = lane >> 4, lr = lane & 15;
    const int q0 = blockIdx.x * 64 + w * 16;
    const int kbs = z * (KL / 2), kbe = kbs + (KL / 2);

    for (int i = t; i < KL / 2; i += 256) mlds[i] = (short)mask[(kbs + i) * BS + b];
    __syncthreads();

    const bf16* qbase = Qb + ((size_t)bn * QL + q0 + lr) * DH;
    const v8s aq0 = *(const v8s*)(qbase + quad * 8);
    const v8s aq1 = *(const v8s*)(qbase + 32 + quad * 8);
    int qs = q0 + 1 + lr; qs = qs > QL - 1 ? QL - 1 : qs;
    const bf16* qsb = Qb + ((size_t)bn * QL + qs) * DH;
    const v8s as0 = *(const v8s*)(qsb + quad * 8);
    const v8s as1 = *(const v8s*)(qsb + 32 + quad * 8);

    const bf16* kbase = Wk + (size_t)bn * KL * DH;
    const bf16* rkb   = Rk + (size_t)n * RL * DH;

    int o_[4], src_[4];
#pragma unroll
    for (int r = 0; r < 4; ++r) {
        const int rho = quad * 4 + r;
        o_[r] = lr - rho;
        src_[r] = (lane & 48) | (o_[r] & 15);
    }

    auto band = [&](int cb, v8s a0, v8s a1) -> v4f {
        int rrow = cb + lr;
        rrow = rrow < 0 ? 0 : (rrow > RL - 1 ? RL - 1 : rrow);
        const bf16* rp = rkb + (size_t)rrow * DH;
        v8s b0 = *(const v8s*)(rp + quad * 8);
        v8s b1 = *(const v8s*)(rp + 32 + quad * 8);
        v4f a = {};
        a = __builtin_amdgcn_mfma_f32_16x16x32_bf16(a0, b0, a, 0, 0, 0);
        a = __builtin_amdgcn_mfma_f32_16x16x32_bf16(a1, b1, a, 0, 0, 0);
        return a;
    };

    v4f TA0, TA1 = {}, TB0, TB1 = {};
    TA0 = band(kbs - 16 - q0 + 2047, aq0, aq1);
    TB0 = band(kbs - 16 - q0 - 2,   as0, as1);

    float pl[4] = {0.f, 0.f, 0.f, 0.f};
    for (int kb = kbs; kb < kbe; kb += 16) {
        const bool useA = (kb <= q0);
        const bool useB = (kb >= q0);
        if (useA) TA1 = band(kb - q0 + 2047, aq0, aq1);
        if (useB) TB1 = band(kb - q0 - 2,   as0, as1);
        const bf16* krow = kbase + (size_t)(kb + lr) * DH;
        v8s bk0 = *(const v8s*)(krow + quad * 8);
        v8s bk1 = *(const v8s*)(krow + 32 + quad * 8);
        v4f ac = {};
        ac = __builtin_amdgcn_mfma_f32_16x16x32_bf16(aq0, bk0, ac, 0, 0, 0);
        ac = __builtin_amdgcn_mfma_f32_16x16x32_bf16(aq1, bk1, ac, 0, 0, 0);
        const bool msk = mlds[kb - kbs + lr] != 0;
#pragma unroll
        for (int r = 0; r < 4; ++r) {
            const int dk = (kb - q0) + o_[r];
            float vA = 0.f, vB = 0.f;
            if (useA) {
                float x0 = __shfl(TA0[r], src_[r], 64);
                float x1 = __shfl(TA1[r], src_[r], 64);
                vA = (o_[r] >= 0) ? x1 : x0;
            }
            if (useB) {
                float x0 = __shfl(TB0[r], src_[r], 64);
                float x1 = __shfl(TB1[r], src_[r], 64);
                vB = (o_[r] >= 0) ? x1 : x0;
            }
            const float bd = (dk <= 0) ? vA : ((dk == 1) ? 0.f : vB);
            const float ex = __expf((ac[r] + bd) * 0.125f);
            pl[r] += msk ? 0.f : ex;
        }
        if (useA) TA0 = TA1;
        if (useB) TB0 = TB1;
    }
#pragma unroll
    for (int r = 0; r < 4; ++r) {
        float l = pl[r];
#pragma unroll
        for (int off = 1; off < 16; off <<= 1) l += __shfl_xor(l, off, 64);
        pl[r] = l;
    }
    if (lr == 0) {
#pragma unroll
        for (int r = 0; r < 4; ++r) {
            const int q = q0 + quad * 4 + r;
            lpart[((size_t)z * 32 + bn) * QL + q] = pl[r];
        }
    }
}

// ---------------------------------------------------------------------------
// Pass B: p = exp(s) / (l0+l1) -> coverage (f32) + PV partial -> AVp.
// Grid (QL/64, 32, 2); AVp[z] merged by gemm64f<0> via A2.
// ---------------------------------------------------------------------------
__global__ __launch_bounds__(256, 6) void attn_passB(
    const bf16* __restrict__ Qb, const bf16* __restrict__ Wk,
    const bf16* __restrict__ Wvt, const bf16* __restrict__ Rk,
    const int* __restrict__ mask, const float* __restrict__ lpart,
    float* __restrict__ cov, float* __restrict__ AVp0,
    float* __restrict__ AVp1)
{
    __shared__ short mlds[KL / 2];
    __shared__ short Plds[4][16][32];     // per-wave-private slices
    const int bn = blockIdx.y, b = bn >> 4, n = bn & 15;
    const int z = blockIdx.z;
    const int t = threadIdx.x, w = t >> 6, lane = t & 63;
    const int quad = lane >> 4, lr = lane & 15;
    const int q0 = blockIdx.x * 64 + w * 16;
    const int kbs = z * (KL / 2), kbe = kbs + (KL / 2);
    float* __restrict__ AV = z ? AVp1 : AVp0;

    for (int i = t; i < KL / 2; i += 256) mlds[i] = (short)mask[(kbs + i) * BS + b];
    __syncthreads();

    // 1/l per owned q row
    float pli[4];
#pragma unroll
    for (int r = 0; r < 4; ++r) {
        const int q = q0 + quad * 4 + r;
        const float lt = lpart[(size_t)bn * QL + q] +
                         lpart[((size_t)32 + bn) * QL + q];
        pli[r] = (lt > 0.f) ? 1.f / lt : 0.f;
    }

    const bf16* qbase = Qb + ((size_t)bn * QL + q0 + lr) * DH;
    const v8s aq0 = *(const v8s*)(qbase + quad * 8);
    const v8s aq1 = *(const v8s*)(qbase + 32 + quad * 8);
    int qs = q0 + 1 + lr; qs = qs > QL - 1 ? QL - 1 : qs;
    const bf16* qsb = Qb + ((size_t)bn * QL + qs) * DH;
    const v8s as0 = *(const v8s*)(qsb + quad * 8);
    const v8s as1 = *(const v8s*)(qsb + 32 + quad * 8);

    const bf16* kbase = Wk + (size_t)bn * KL * DH;
    const bf16* rkb   = Rk + (size_t)n * RL * DH;
    float* covb = cov + (size_t)bn * QL * KL;

    int o_[4], src_[4];
#pragma unroll
    for (int r = 0; r < 4; ++r) {
        const int rho = quad * 4 + r;
        o_[r] = lr - rho;
        src_[r] = (lane & 48) | (o_[r] & 15);
    }

    auto band = [&](int cb, v8s a0, v8s a1) -> v4f {
        int rrow = cb + lr;
        rrow = rrow < 0 ? 0 : (rrow > RL - 1 ? RL - 1 : rrow);
        const bf16* rp = rkb + (size_t)rrow * DH;
        v8s b0 = *(const v8s*)(rp + quad * 8);
        v8s b1 = *(const v8s*)(rp + 32 + quad * 8);
        v4f a = {};
        a = __builtin_amdgcn_mfma_f32_16x16x32_bf16(a0, b0, a, 0, 0, 0);
        a = __builtin_amdgcn_mfma_f32_16x16x32_bf16(a1, b1, a, 0, 0, 0);
        return a;
    };

    v4f TA0, TA1 = {}, TB0, TB1 = {};
    TA0 = band(kbs - 16 - q0 + 2047, aq0, aq1);
    TB0 = band(kbs - 16 - q0 - 2,   as0, as1);

    v4f accv[4] = {};
    for (int kb = kbs; kb < kbe; kb += 16) {
        const bool useA = (kb <= q0);
        const bool useB = (kb >= q0);
        if (useA) TA1 = band(kb - q0 + 2047, aq0, aq1);
        if (useB) TB1 = band(kb - q0 - 2,   as0, as1);
        const bf16* krow = kbase + (size_t)(kb + lr) * DH;
        v8s bk0 = *(const v8s*)(krow + quad * 8);
        v8s bk1 = *(const v8s*)(krow + 32 + quad * 8);
        v4f ac = {};
        ac = __builtin_amdgcn_mfma_f32_16x16x32_bf16(aq0, bk0, ac, 0, 0, 0);
        ac = __builtin_amdgcn_mfma_f32_16x16x32_bf16(aq1, bk1, ac, 0, 0, 0);
        const bool msk = mlds[kb - kbs + lr] != 0;
        const int tt = (kb >> 4) & 1;
#pragma unroll
        for (int r = 0; r < 4; ++r) {
            const int dk = (kb - q0) + o_[r];
            float vA = 0.f, vB = 0.f;
            if (useA) {
                float x0 = __shfl(TA0[r], src_[r], 64);
                float x1 = __shfl(TA1[r], src_[r], 64);
                vA = (o_[r] >= 0) ? x1 : x0;
            }
            if (useB) {
                float x0 = __shfl(TB0[r], src_[r], 64);
                float x1 = __shfl(TB1[r], src_[r], 64);
                vB = (o_[r] >= 0) ? x1 : x0;
            }
            const float bd = (dk <= 0) ? vA : ((dk == 1) ? 0.f : vB);
            const float ex = __expf((ac[r] + bd) * 0.125f);
            const float p = (msk ? 0.f : ex) * pli[r];
            const int q = q0 + quad * 4 + r;
            covb[(size_t)q * KL + kb + lr] = p;
            Plds[w][quad * 4 + r][tt * 16 + lr] = f2s(p);
        }
        if (useA) TA0 = TA1;
        if (useB) TB0 = TB1;
        if (tt == 1) {
            // Plds[w] is wave-private: in-wave DS ordering suffices, no barrier
            v8s ap = *(const v8s*)&Plds[w][lr][quad * 8];
            const int k0 = kb & ~31;
#pragma unroll
            for (int dt = 0; dt < 4; ++dt) {
                const bf16* vrow = Wvt + ((size_t)bn * DH + dt * 16 + lr) * KL + k0 + quad * 8;
                v8s bv = *(const v8s*)vrow;
                accv[dt] = __builtin_amdgcn_mfma_f32_16x16x32_bf16(ap, bv, accv[dt], 0, 0, 0);
            }
        }
    }

#pragma unroll
    for (int dt = 0; dt < 4; ++dt) {
#pragma unroll
        for (int r = 0; r < 4; ++r) {
            const int q = q0 + quad * 4 + r;
            AV[((size_t)q * BS + b) * DM + n * DH + dt * 16 + lr] = accv[dt][r];
        }
    }
}

extern "C" void kernel_launch(void* const* d_in, const int* in_sizes, int n_in,
                              void* d_out, int out_size, void* d_ws, size_t ws_size,
                              hipStream_t stream)
{
    const float* w     = (const float*)d_in[0];   // (2048, 2, 1024) f32
    const float* r     = (const float*)d_in[1];   // (2048, 1024) f32
    const int*   mask  = (const int*)d_in[2];     // (2048, 2) bool->int32
    const float* qkvw  = (const float*)d_in[3];   // (1024, 3072) f32
    const float* rnetw = (const float*)d_in[4];   // (1024, 1024) f32
    const float* ow    = (const float*)d_in[5];   // (1024, 1024) f32
    const float* rrb   = (const float*)d_in[7];   // (16, 64) f32 (d_in[6] unused: ref bug)

    char* ws = (char*)d_ws;
    bf16*  Qb   = (bf16*)(ws);                        // [b][n][q][d] bf16   8 MiB
    bf16*  Wk   = (bf16*)(ws + ((size_t)8  << 20));   // [b][n][k][d] bf16   8 MiB
    bf16*  Wvt  = (bf16*)(ws + ((size_t)16 << 20));   // [b][n][d][k] bf16   8 MiB
    bf16*  Rk   = (bf16*)(ws + ((size_t)24 << 20));   // [n][r][d] bf16      4 MiB
    float* AVp0 = (float*)(ws + ((size_t)28 << 20));  // [q][b][1024] f32   16 MiB
    float* AVp1 = (float*)(ws + ((size_t)44 << 20));  // [q][b][1024] f32   16 MiB
    float* lpart = (float*)(ws + ((size_t)60 << 20)); // [2][32][2048] f32 512 KiB
    // total ws use: 60.5 MiB

    float* out_main = (float*)d_out;                      // (2048, 2, 1024) f32
    float* out_cov  = out_main + (size_t)QL * BS * DM;    // (2,16,2048,2048) f32

    // 1) heads = w @ qkv_w, scatter Qb(+bias)/Wk/Wvt
    gemm64f<1><<<dim3(48, 64), 256, 0, stream>>>(w, nullptr, qkvw, 4096, 3072, 1024,
                                                 nullptr, Qb, Wk, Wvt, nullptr, rrb);
    // 2) Rk = r @ r_net_w
    gemm64f<2><<<dim3(16, 32), 256, 0, stream>>>(r, nullptr, rnetw, 2048, 1024, 1024,
                                                 nullptr, nullptr, nullptr, nullptr, Rk, nullptr);
    // 3) softmax denominators (k-split x2 across blocks)
    attn_passA<<<dim3(32, 32, 2), 256, 0, stream>>>(Qb, Wk, Rk, mask, lpart);
    // 4) p/coverage/PV partials (k-split x2 across blocks)
    attn_passB<<<dim3(32, 32, 2), 256, 0, stream>>>(Qb, Wk, Wvt, Rk, mask, lpart,
                                                    out_cov, AVp0, AVp1);
    // 5) output = (AVp0+AVp1) @ o_w
    gemm64f<0><<<dim3(16, 64), 256, 0, stream>>>(AVp0, AVp1, ow, 4096, 1024, 1024,
                                                 out_main, nullptr, nullptr, nullptr, nullptr, nullptr);
}

// Round 4
// 1334.286 us; speedup vs baseline: 1.3111x; 1.3111x over previous
//
#include <hip/hip_runtime.h>
#include <hip/hip_bf16.h>

// RelPartialLearnableMultiHeadAttn (Transformer-XL) on MI355X.
// Shapes: QLEN=KLEN=RLEN=2048, BSZ=2, NH=16, DH=64, DM=1024. SCALE=0.125.
// R7: R6's cross-kernel k-split REGRESSED (FETCH 277->790 MB, zero L2 reuse)
// -- attn reverted to the proven R4 fused kernel (692 us). This round attacks
// the other half of the runtime: the 64^2-tile GEMMs ran at ~60 TF (~670 us
// for 38.7 GFLOP). Replaced with a 128x128-tile BK=32 4-wave GEMM:
//  - 16 MFMAs/wave/step (4x4 fragments), LDS stride 72 el (144 B: 16B-aligned
//    b128 ops, 2-way bank conflict = free)
//  - B transposed in staging via packed ds_write_b64 (was 8 scalar b16)
//  - f32->bf16 cvt in registers during staging
//  - attn writes AV directly as bf16 (same rounding; halves AV traffic)

#define QL 2048
#define KL 2048
#define RL 2048
#define BS 2
#define NHD 16
#define DH 64
#define DM 1024

typedef __hip_bfloat16 bf16;
typedef short v4s __attribute__((ext_vector_type(4)));
typedef short v8s __attribute__((ext_vector_type(8)));
typedef float v4f __attribute__((ext_vector_type(4)));

__device__ __forceinline__ bf16 f2b(float x) { return __float2bfloat16(x); }
__device__ __forceinline__ short f2s(float x) {
    return __builtin_bit_cast(short, __float2bfloat16(x));
}

// ---------------------------------------------------------------------------
// 128x128-tile GEMM, C = A(MxK) @ B(KxN); B row-major f32, converted to bf16
// and transposed into LDS during staging. A is f32 (EPI 1/2) or bf16 (EPI 0).
// 4 waves, each computes a 64x64 quadrant as 4x4 16x16x32 MFMA fragments.
// EPI 0: f32 C write. EPI 1: qkv scatter (+r_r_bias into Qb; Wv transposed),
// bf16 out. EPI 2: Rk scatter [n][r][d], bf16 out.
// Requires M%128==0, N%128==0, K%32==0.
// ---------------------------------------------------------------------------
template <int EPI>
__global__ __launch_bounds__(256) void gemm128(
    const void* __restrict__ Avoid, const float* __restrict__ B,
    int M, int N, int K,
    float* __restrict__ C,
    bf16* __restrict__ Qb, bf16* __restrict__ Wk, bf16* __restrict__ Wvt,
    bf16* __restrict__ Rk, const float* __restrict__ rrb)
{
    // stride 72 el = 144 B: 16B-aligned (b128 ok), 36 banks/row -> 2-way
    // conflict on 16-lane fragment reads (free per m136).
    __shared__ short As[128][72];
    __shared__ short Bs[128][72];   // transposed: Bs[n][k]
    const int n0 = blockIdx.x * 128, m0 = blockIdx.y * 128;
    const int t = threadIdx.x, w = t >> 6, lane = t & 63;
    const int quad = lane >> 4, lr = lane & 15;
    const int wm = w >> 1, wn = w & 1;

    v4f acc[4][4] = {};
    for (int k0 = 0; k0 < K; k0 += 32) {
        {   // ---- A tile 128x32 -> LDS (row-major) ----
            const int row = t >> 1, kh = (t & 1) << 4;   // 16 cols per thread
            if constexpr (EPI == 0) {
                const bf16* ap = (const bf16*)Avoid + (size_t)(m0 + row) * K + k0 + kh;
                *(v8s*)&As[row][kh]     = *(const v8s*)ap;
                *(v8s*)&As[row][kh + 8] = *(const v8s*)(ap + 8);
            } else {
                const float* ap = (const float*)Avoid + (size_t)(m0 + row) * K + k0 + kh;
                float4 a0 = *(const float4*)ap;
                float4 a1 = *(const float4*)(ap + 4);
                float4 a2 = *(const float4*)(ap + 8);
                float4 a3 = *(const float4*)(ap + 12);
                v8s p0, p1;
                p0[0] = f2s(a0.x); p0[1] = f2s(a0.y); p0[2] = f2s(a0.z); p0[3] = f2s(a0.w);
                p0[4] = f2s(a1.x); p0[5] = f2s(a1.y); p0[6] = f2s(a1.z); p0[7] = f2s(a1.w);
                p1[0] = f2s(a2.x); p1[1] = f2s(a2.y); p1[2] = f2s(a2.z); p1[3] = f2s(a2.w);
                p1[4] = f2s(a3.x); p1[5] = f2s(a3.y); p1[6] = f2s(a3.z); p1[7] = f2s(a3.w);
                *(v8s*)&As[row][kh]     = p0;
                *(v8s*)&As[row][kh + 8] = p1;
            }
            // ---- B tile 32x128 -> LDS transposed [n][k] ----
            // thread: rows kk..kk+3, cols nn..nn+3; pack 4 k-values -> b64
            const int kk = (t & 7) << 2, nn = (t >> 3) << 2;
            const float* bp = B + (size_t)(k0 + kk) * N + n0 + nn;
            float4 b0 = *(const float4*)bp;
            float4 b1 = *(const float4*)(bp + N);
            float4 b2 = *(const float4*)(bp + 2 * N);
            float4 b3 = *(const float4*)(bp + 3 * N);
            v4s c;
            c[0] = f2s(b0.x); c[1] = f2s(b1.x); c[2] = f2s(b2.x); c[3] = f2s(b3.x);
            *(v4s*)&Bs[nn + 0][kk] = c;
            c[0] = f2s(b0.y); c[1] = f2s(b1.y); c[2] = f2s(b2.y); c[3] = f2s(b3.y);
            *(v4s*)&Bs[nn + 1][kk] = c;
            c[0] = f2s(b0.z); c[1] = f2s(b1.z); c[2] = f2s(b2.z); c[3] = f2s(b3.z);
            *(v4s*)&Bs[nn + 2][kk] = c;
            c[0] = f2s(b0.w); c[1] = f2s(b1.w); c[2] = f2s(b2.w); c[3] = f2s(b3.w);
            *(v4s*)&Bs[nn + 3][kk] = c;
        }
        __syncthreads();
        v8s af[4], bfr[4];
#pragma unroll
        for (int i = 0; i < 4; ++i)
            af[i] = *(const v8s*)&As[wm * 64 + i * 16 + lr][quad * 8];
#pragma unroll
        for (int j = 0; j < 4; ++j)
            bfr[j] = *(const v8s*)&Bs[wn * 64 + j * 16 + lr][quad * 8];
#pragma unroll
        for (int i = 0; i < 4; ++i)
#pragma unroll
            for (int j = 0; j < 4; ++j)
                acc[i][j] = __builtin_amdgcn_mfma_f32_16x16x32_bf16(af[i], bfr[j], acc[i][j], 0, 0, 0);
        __syncthreads();
    }

#pragma unroll
    for (int i = 0; i < 4; ++i) {
#pragma unroll
        for (int j = 0; j < 4; ++j) {
#pragma unroll
            for (int r = 0; r < 4; ++r) {
                const int gm = m0 + wm * 64 + i * 16 + quad * 4 + r;  // C row
                const int gn = n0 + wn * 64 + j * 16 + lr;            // C col
                float v = acc[i][j][r];
                if constexpr (EPI == 0) {
                    C[(size_t)gm * N + gn] = v;
                } else if constexpr (EPI == 1) {
                    const int q = gm >> 1, b = gm & 1;   // w rows are (q, b)
                    const int sec = gn >> 10, idx = gn & 1023;
                    const int n = idx >> 6, d = idx & 63;
                    const size_t bn = (size_t)(b * NHD + n);
                    if (sec == 0) {
                        v += rrb[n * 64 + d];            // Qb = wq + r_r_bias
                        Qb[(bn * QL + q) * DH + d] = f2b(v);
                    } else if (sec == 1) {
                        Wk[(bn * KL + q) * DH + d] = f2b(v);
                    } else {
                        Wvt[(bn * DH + d) * KL + q] = f2b(v); // transposed [d][k]
                    }
                } else {  // EPI == 2 : Rk[n][r][d]
                    const int n = gn >> 6, d = gn & 63;
                    Rk[((size_t)n * RL + gm) * DH + d] = f2b(v);
                }
            }
        }
    }
}

// ---------------------------------------------------------------------------
// Fused BD + scores + softmax + coverage + PV per (b,n, 64-row q block).
// Exact R4 structure (best measured: 692 us); only change: AV written bf16.
// ---------------------------------------------------------------------------
__global__ __launch_bounds__(256) void attn_kernel(
    const bf16* __restrict__ Qb, const bf16* __restrict__ Wk,
    const bf16* __restrict__ Wvt, const bf16* __restrict__ Rk,
    const int* __restrict__ mask,
    float* __restrict__ cov, bf16* __restrict__ AV)
{
    __shared__ short Plds[4][16][32];
    __shared__ int mlds[KL];
    const int bn = blockIdx.y, b = bn >> 4, n = bn & 15;
    const int t = threadIdx.x, w = t >> 6, lane = t & 63;
    const int quad = lane >> 4, lr = lane & 15;
    const int q0 = blockIdx.x * 64 + 16 * w;   // wave's 16-row q-tile base

    for (int i = t; i < KL; i += 256) mlds[i] = mask[i * BS + b];
    __syncthreads();

    const bf16* qbase = Qb + ((size_t)bn * QL + q0 + lr) * DH;
    const v8s aq0 = *(const v8s*)(qbase + quad * 8);
    const v8s aq1 = *(const v8s*)(qbase + 32 + quad * 8);
    int qs = q0 + 1 + lr; qs = qs > QL - 1 ? QL - 1 : qs;
    const bf16* qsb = Qb + ((size_t)bn * QL + qs) * DH;
    const v8s as0 = *(const v8s*)(qsb + quad * 8);
    const v8s as1 = *(const v8s*)(qsb + 32 + quad * 8);

    const bf16* kbase = Wk + (size_t)bn * KL * DH;
    const bf16* rkb   = Rk + (size_t)n * RL * DH;
    float* covb = cov + (size_t)bn * QL * KL;

    const v4f vzero = {};

    auto band = [&](int cb, v8s a0, v8s a1) -> v4f {
        int rrow = cb + lr;
        rrow = rrow < 0 ? 0 : (rrow > RL - 1 ? RL - 1 : rrow);
        const bf16* rp = rkb + (size_t)rrow * DH;
        v8s b0 = *(const v8s*)(rp + quad * 8);
        v8s b1 = *(const v8s*)(rp + 32 + quad * 8);
        v4f a = {};
        a = __builtin_amdgcn_mfma_f32_16x16x32_bf16(a0, b0, a, 0, 0, 0);
        a = __builtin_amdgcn_mfma_f32_16x16x32_bf16(a1, b1, a, 0, 0, 0);
        return a;
    };

    v4f TA0, TA1, TB0, TB1;

    auto scores = [&](int kb, float* s) {
        const bool useA = (kb <= q0);   // wave-uniform
        const bool useB = (kb >= q0);
        if (useA) TA1 = band(kb - q0 + 2047, aq0, aq1);
        if (useB) TB1 = band(kb - q0 - 2,   as0, as1);
        const bf16* krow = kbase + (size_t)(kb + lr) * DH;
        v8s bk0 = *(const v8s*)(krow + quad * 8);
        v8s bk1 = *(const v8s*)(krow + 32 + quad * 8);
        v4f ac = {};
        ac = __builtin_amdgcn_mfma_f32_16x16x32_bf16(aq0, bk0, ac, 0, 0, 0);
        ac = __builtin_amdgcn_mfma_f32_16x16x32_bf16(aq1, bk1, ac, 0, 0, 0);
        const bool msk = mlds[kb + lr] != 0;
#pragma unroll
        for (int r = 0; r < 4; ++r) {
            const int rho = quad * 4 + r;          // tile-local q row
            const int o = lr - rho;                // col - row, in [-15,15]
            const int dk = (kb - q0) + o;          // k - q
            const int src = (lane & 48) | (o & 15);
            float vA = 0.f, vB = 0.f;
            if (useA) {
                float x0 = __shfl(TA0[r], src, 64);
                float x1 = __shfl(TA1[r], src, 64);
                vA = (o >= 0) ? x1 : x0;
            }
            if (useB) {
                float x0 = __shfl(TB0[r], src, 64);
                float x1 = __shfl(TB1[r], src, 64);
                vB = (o >= 0) ? x1 : x0;
            }
            const float bd = (dk <= 0) ? vA : ((dk == 1) ? 0.f : vB);
            s[r] = msk ? -1.0e30f : (ac[r] + bd) * 0.125f;
        }
        TA0 = TA1;
        TB0 = TB1;
    };

    // ---- pass A: online max/sum ----
    float pm[4], pl[4];
#pragma unroll
    for (int r = 0; r < 4; ++r) { pm[r] = -3.0e38f; pl[r] = 0.f; }
    TA0 = band(2047 - q0 - 16, aq0, aq1);
    TA1 = vzero; TB0 = vzero; TB1 = vzero;
    for (int kb = 0; kb < KL; kb += 16) {
        float s[4];
        scores(kb, s);
#pragma unroll
        for (int r = 0; r < 4; ++r) {
            const float nm = fmaxf(pm[r], s[r]);
            pl[r] = pl[r] * __expf(pm[r] - nm) + __expf(s[r] - nm);
            pm[r] = nm;
        }
    }
#pragma unroll
    for (int r = 0; r < 4; ++r) {
        float m = pm[r], l = pl[r];
#pragma unroll
        for (int off = 1; off < 16; off <<= 1) {
            float om = __shfl_xor(m, off, 64);
            float ol = __shfl_xor(l, off, 64);
            float nm = fmaxf(m, om);
            l = l * __expf(m - nm) + ol * __expf(om - nm);
            m = nm;
        }
        pm[r] = m;
        pl[r] = (l > 0.f) ? 1.f / l : 0.f;
    }

    // ---- pass B: normalized P write (f32 coverage) + PV ----
    v4f accv[4] = {};
    TA0 = band(2047 - q0 - 16, aq0, aq1);
    TA1 = vzero; TB0 = vzero; TB1 = vzero;
    for (int kb = 0; kb < KL; kb += 16) {
        float s[4];
        scores(kb, s);
        const int tt = (kb >> 4) & 1;
#pragma unroll
        for (int r = 0; r < 4; ++r) {
            const int q = q0 + quad * 4 + r;
            const float p = __expf(s[r] - pm[r]) * pl[r];
            covb[(size_t)q * KL + kb + lr] = p;
            Plds[w][quad * 4 + r][tt * 16 + lr] = f2s(p);
        }
        if (tt == 1) {
            // Plds[w] is wave-private: in-wave DS ordering suffices, no barrier
            v8s ap = *(const v8s*)&Plds[w][lr][quad * 8];
            const int k0 = kb & ~31;
#pragma unroll
            for (int dt = 0; dt < 4; ++dt) {
                const bf16* vrow = Wvt + ((size_t)bn * DH + dt * 16 + lr) * KL + k0 + quad * 8;
                v8s bv = *(const v8s*)vrow;
                accv[dt] = __builtin_amdgcn_mfma_f32_16x16x32_bf16(ap, bv, accv[dt], 0, 0, 0);
            }
        }
    }

    // attn_vec: AV[q][b][n*64+d]  (bf16; feeds the bf16 output GEMM directly)
#pragma unroll
    for (int dt = 0; dt < 4; ++dt) {
#pragma unroll
        for (int r = 0; r < 4; ++r) {
            const int q = q0 + quad * 4 + r;
            AV[((size_t)q * BS + b) * DM + n * DH + dt * 16 + lr] = f2b(accv[dt][r]);
        }
    }
}

extern "C" void kernel_launch(void* const* d_in, const int* in_sizes, int n_in,
                              void* d_out, int out_size, void* d_ws, size_t ws_size,
                              hipStream_t stream)
{
    const float* w     = (const float*)d_in[0];   // (2048, 2, 1024) f32
    const float* r     = (const float*)d_in[1];   // (2048, 1024) f32
    const int*   mask  = (const int*)d_in[2];     // (2048, 2) bool->int32
    const float* qkvw  = (const float*)d_in[3];   // (1024, 3072) f32
    const float* rnetw = (const float*)d_in[4];   // (1024, 1024) f32
    const float* ow    = (const float*)d_in[5];   // (1024, 1024) f32
    const float* rrb   = (const float*)d_in[7];   // (16, 64) f32 (d_in[6] unused: ref bug)

    char* ws = (char*)d_ws;
    bf16*  Qb  = (bf16*)(ws);                        // [b][n][q][d] bf16   8 MiB
    bf16*  Wk  = (bf16*)(ws + ((size_t)8  << 20));   // [b][n][k][d] bf16   8 MiB
    bf16*  Wvt = (bf16*)(ws + ((size_t)16 << 20));   // [b][n][d][k] bf16   8 MiB
    bf16*  Rk  = (bf16*)(ws + ((size_t)24 << 20));   // [n][r][d] bf16      4 MiB
    bf16*  AVb = (bf16*)(ws + ((size_t)28 << 20));   // [q*2+b][1024] bf16  8 MiB
    // total ws use: 36 MiB

    float* out_main = (float*)d_out;                      // (2048, 2, 1024) f32
    float* out_cov  = out_main + (size_t)QL * BS * DM;    // (2,16,2048,2048) f32

    // 1) heads = w @ qkv_w, scatter Qb(+bias)/Wk/Wvt
    gemm128<1><<<dim3(24, 32), 256, 0, stream>>>(w, qkvw, 4096, 3072, 1024,
                                                 nullptr, Qb, Wk, Wvt, nullptr, rrb);
    // 2) Rk = r @ r_net_w
    gemm128<2><<<dim3(8, 16), 256, 0, stream>>>(r, rnetw, 2048, 1024, 1024,
                                                nullptr, nullptr, nullptr, nullptr, Rk, nullptr);
    // 3) fused BD + scores + softmax + coverage + PV (R4 structure)
    attn_kernel<<<dim3(32, 32), 256, 0, stream>>>(Qb, Wk, Wvt, Rk, mask, out_cov, AVb);
    // 4) output = AV @ o_w  (A is bf16)
    gemm128<0><<<dim3(8, 32), 256, 0, stream>>>(AVb, ow, 4096, 1024, 1024,
                                                out_main, nullptr, nullptr, nullptr, nullptr, nullptr);
}